// Round 5
// baseline (287.114 us; speedup 1.0000x reference)
//
#include <hip/hip_runtime.h>
#include <math.h>

#define CHI 64
#define CHO 64
#define HH 128
#define WW 128
#define NB 4
#define KK 9
#define NOFF 27
#define NOFFP 28              // padded for float2 packing
#define EPSV 1e-5f
#define PLANE (HH * WW)

// packed-fp32 vector types
typedef float v2f __attribute__((ext_vector_type(2)));
// bilinear pair load: only 4-byte alignment guaranteed
typedef float f2v __attribute__((ext_vector_type(2), aligned(4)));

__device__ __forceinline__ v2f pkfma(v2f a, v2f b, v2f c) {
#if __has_builtin(__builtin_elementwise_fma)
    return __builtin_elementwise_fma(a, b, c);
#else
    return a * b + c;
#endif
}

// ---------------- prep: weight transposes ----------------
// w_t[kk][ci][co]   = w[co][ci][kk]          (9*64*64 = 36864 floats)
// wo_t[ci][tap][c28] = w_off[c][ci][tap]     (64*9*28 = 16128 floats, c=27 -> 0)
__global__ __launch_bounds__(256) void prep_kernel(const float* __restrict__ w,
                                                   const float* __restrict__ w_off,
                                                   float* __restrict__ w_t,
                                                   float* __restrict__ wo_t) {
    int i = blockIdx.x * 256 + threadIdx.x;
    if (i < CHO * CHI * KK) {
        int kk = i / (CHI * CHO);
        int r  = i % (CHI * CHO);
        int ci = r / CHO;
        int co = r % CHO;
        w_t[i] = w[(co * CHI + ci) * KK + kk];
    }
    if (i < CHI * KK * NOFFP) {
        int ci  = i / (KK * NOFFP);
        int r   = i % (KK * NOFFP);
        int tap = r / NOFFP;
        int c   = r % NOFFP;
        wo_t[i] = (c < NOFF) ? w_off[(c * CHI + ci) * KK + tap] : 0.f;
    }
}

// ---------------- offset conv ----------------
// 512 threads: w = tid&127, chunk = tid>>7 (4 chunks x 16 ci, SGPR-forced).
// grid 512: blockIdx%8 -> (b, h-half) for XCD L2 locality.
// Loads staged per plane (9 in flight) before FMAs for MLP.
__global__ __launch_bounds__(512) void off_conv_kernel(const float* __restrict__ x,
                                                       const float* __restrict__ wo_t,
                                                       float* __restrict__ off) {
    const int id    = blockIdx.x;
    const int slot  = id & 7;
    const int b     = slot & 3;
    const int h     = (slot >> 2) * 64 + (id >> 3);
    const int w     = threadIdx.x & 127;
    // wave-uniform (flips every 128 = 2 waves) -> force SGPR for scalar weights
    const int chunk = __builtin_amdgcn_readfirstlane(threadIdx.x >> 7);

    v2f acc[NOFFP / 2];
#pragma unroll
    for (int c = 0; c < NOFFP / 2; c++) acc[c] = (v2f)(0.f);

    const float* xb  = x + ((size_t)b * CHI + chunk * 16) * PLANE;
    const float* wob = wo_t + chunk * 16 * KK * NOFFP;

    for (int ci = 0; ci < 16; ci++) {
        const float* plane = xb + ci * PLANE;
        float xv[KK];
        // stage all 9 taps first -> 9 loads in flight
#pragma unroll
        for (int ky = 0; ky < 3; ky++) {
            int hr = h - 1 + ky;
            bool rok = (unsigned)hr < HH;
#pragma unroll
            for (int kx = 0; kx < 3; kx++) {
                int wc = w - 1 + kx;
                xv[ky * 3 + kx] = (rok && (unsigned)wc < WW) ? plane[hr * WW + wc] : 0.f;
            }
        }
#pragma unroll
        for (int t = 0; t < KK; t++) {
            v2f xv2 = {xv[t], xv[t]};
            const v2f* wp = (const v2f*)(wob + (ci * KK + t) * NOFFP);
#pragma unroll
            for (int c = 0; c < NOFFP / 2; c++) acc[c] = pkfma(xv2, wp[c], acc[c]);
        }
    }

    __shared__ v2f lacc[3][128][NOFFP / 2];   // 43008 B
    if (chunk > 0) {
#pragma unroll
        for (int c = 0; c < NOFFP / 2; c++) lacc[chunk - 1][w][c] = acc[c];
    }
    __syncthreads();
    if (chunk == 0) {
#pragma unroll
        for (int c = 0; c < NOFFP / 2; c++)
            acc[c] = acc[c] + lacc[0][w][c] + lacc[1][w][c] + lacc[2][w][c];
        float* accs = (float*)acc;
#pragma unroll
        for (int c = 0; c < NOFF; c++)
            off[(((size_t)b * NOFF + c) * HH + h) * WW + w] = accs[c];
    }
}

// ---------------- deform sample + main conv ----------------
// 512 threads: px = tid&255 (2 rows x 128), cih = tid>>8 (ci half, SGPR-forced).
// grid 512: blockIdx%8 -> (b, co_half) for XCD L2 locality; hp = id>>3.
// Inner loop: 8 planes staged (16 dwordx2 in flight) before consumption.
__global__ __launch_bounds__(512) void deform_kernel(const float* __restrict__ x,
                                                     const float* __restrict__ w_t,
                                                     const float* __restrict__ off,
                                                     const float* __restrict__ b_off,
                                                     const float* __restrict__ bias,
                                                     float* __restrict__ out) {
    const int id      = blockIdx.x;
    const int slot    = id & 7;
    const int b       = slot >> 1;
    const int co_base = (slot & 1) * 32;
    const int hp      = id >> 3;                       // 0..63
    const int px      = threadIdx.x & 255;
    // wave-uniform (flips at tid=256, wave boundary) -> SGPR so weight reads
    // stay s_load (R3 lesson: VGPR-based weight base => 3x slowdown)
    const int cih     = __builtin_amdgcn_readfirstlane(threadIdx.x >> 8);
    const int h       = hp * 2 + (px >> 7);
    const int w       = px & 127;

    v2f acc[16];
#pragma unroll
    for (int j = 0; j < 16; j++) acc[j] = (v2f)(0.f);

    const float* xb   = x + ((size_t)b * CHI + cih * 32) * PLANE;
    const float* offb = off + (size_t)b * NOFF * PLANE + h * WW + w;

#pragma unroll
    for (int kk = 0; kk < KK; kk++) {
        const int ky = kk / 3, kx = kk % 3;
        float dy = offb[(2 * kk) * PLANE]     + b_off[2 * kk];
        float dx = offb[(2 * kk + 1) * PLANE] + b_off[2 * kk + 1];
        float mo = offb[(18 + kk) * PLANE]    + b_off[18 + kk];
        float m  = 1.f / (1.f + __expf(-mo));

        float py = (float)(h - 1 + ky) + dy;
        float px_ = (float)(w - 1 + kx) + dx;
        float fy0 = floorf(py), fx0 = floorf(px_);
        float wy = py - fy0, wx = px_ - fx0;
        int y0 = (int)fy0, x0 = (int)fx0;
        int y1 = y0 + 1, x1 = x0 + 1;
        bool vy0 = (unsigned)y0 < HH, vy1 = (unsigned)y1 < HH;
        bool vx0 = (unsigned)x0 < WW, vx1 = (unsigned)x1 < WW;
        float a00 = (vy0 && vx0) ? (1.f - wy) * (1.f - wx) * m : 0.f;
        float a01 = (vy0 && vx1) ? (1.f - wy) * wx * m : 0.f;
        float a10 = (vy1 && vx0) ? wy * (1.f - wx) * m : 0.f;
        float a11 = (vy1 && vx1) ? wy * wx * m : 0.f;

        // column-pair: one dwordx2 per row, boundary select folded into weights
        int xbc = min(max(x0, 0), WW - 2);
        bool sel = (x0 == xbc);
        v2f cA = { sel ? a00 : a01, sel ? a01 : a00 };
        v2f cB = { sel ? a10 : a11, sel ? a11 : a10 };
        int cy0 = min(max(y0, 0), HH - 1), cy1 = min(max(y1, 0), HH - 1);
        const int o0 = cy0 * WW + xbc;
        const int o1 = cy1 * WW + xbc;

        const float* pl = xb;
        const float* wk = w_t + (((size_t)kk * CHI) + cih * 32) * CHO + co_base;
#pragma unroll
        for (int cb = 0; cb < 32; cb += 8) {
            f2v q0[8], q1[8];
#pragma unroll
            for (int u = 0; u < 8; u++) {      // 16 loads issued back-to-back
                q0[u] = *(const f2v*)(pl + u * PLANE + o0);
                q1[u] = *(const f2v*)(pl + u * PLANE + o1);
            }
#pragma unroll
            for (int u = 0; u < 8; u++) {
                v2f t = pkfma((v2f)q1[u], cB, (v2f)q0[u] * cA);
                float val = t.x + t.y;
                v2f val2 = {val, val};
                const v2f* wp = (const v2f*)(wk + (cb + u) * CHO);  // s_load
#pragma unroll
                for (int j = 0; j < 16; j++) acc[j] = pkfma(val2, wp[j], acc[j]);
            }
            pl += 8 * PLANE;
        }
    }

    __shared__ v2f lacc[256][17];   // 34816 B, padded stride vs bank conflicts
    if (cih == 1) {
#pragma unroll
        for (int j = 0; j < 16; j++) lacc[px][j] = acc[j];
    }
    __syncthreads();
    if (cih == 0) {
        float* outp = out + (((size_t)b * CHO + co_base) * HH + h) * WW + w;
#pragma unroll
        for (int j = 0; j < 16; j++) {
            v2f s = acc[j] + lacc[px][j];
            outp[(2 * j) * PLANE]     = s.x + bias[co_base + 2 * j];
            outp[(2 * j + 1) * PLANE] = s.y + bias[co_base + 2 * j + 1];
        }
    }
}

// ---------------- per-channel stats (sum, sumsq) ----------------
__global__ __launch_bounds__(256) void stats_kernel(const float* __restrict__ y,
                                                    float* __restrict__ stats) {
    const int co = blockIdx.x;
    const int b  = blockIdx.y;
    const float4* p4 = (const float4*)(y + ((size_t)b * CHO + co) * PLANE);
    float s = 0.f, s2 = 0.f;
    for (int i = threadIdx.x; i < PLANE / 4; i += 256) {
        float4 v = p4[i];
        s  += v.x + v.y + v.z + v.w;
        s2 += v.x * v.x + v.y * v.y + v.z * v.z + v.w * v.w;
    }
#pragma unroll
    for (int o = 32; o > 0; o >>= 1) {
        s  += __shfl_down(s, o, 64);
        s2 += __shfl_down(s2, o, 64);
    }
    __shared__ float ls[4], ls2[4];
    int lane = threadIdx.x & 63, wv = threadIdx.x >> 6;
    if (lane == 0) { ls[wv] = s; ls2[wv] = s2; }
    __syncthreads();
    if (threadIdx.x == 0) {
        float ts = 0.f, t2 = 0.f;
#pragma unroll
        for (int i = 0; i < 4; i++) { ts += ls[i]; t2 += ls2[i]; }
        atomicAdd(&stats[co], ts);
        atomicAdd(&stats[64 + co], t2);
    }
}

// ---------------- BN + ReLU, in place on d_out ----------------
__global__ __launch_bounds__(256) void bn_kernel(float* __restrict__ y,
                                                 const float* __restrict__ stats,
                                                 const float* __restrict__ gamma,
                                                 const float* __restrict__ beta) {
    size_t base = (size_t)blockIdx.x * 1024;           // 16 blocks per (b,co) plane
    int co = (int)((base >> 14) & 63);
    const float inv_n = 1.f / 65536.f;
    float mean = stats[co] * inv_n;
    float var  = stats[64 + co] * inv_n - mean * mean;
    float sc = gamma[co] * rsqrtf(var + EPSV);
    float sh = beta[co] - mean * sc;
    float4* p = (float4*)(y + base);
    float4 v = p[threadIdx.x];
    v.x = fmaxf(fmaf(v.x, sc, sh), 0.f);
    v.y = fmaxf(fmaf(v.y, sc, sh), 0.f);
    v.z = fmaxf(fmaf(v.z, sc, sh), 0.f);
    v.w = fmaxf(fmaf(v.w, sc, sh), 0.f);
    p[threadIdx.x] = v;
}

extern "C" void kernel_launch(void* const* d_in, const int* in_sizes, int n_in,
                              void* d_out, int out_size, void* d_ws, size_t ws_size,
                              hipStream_t stream) {
    const float* x     = (const float*)d_in[0];
    const float* w_off = (const float*)d_in[1];
    const float* b_off = (const float*)d_in[2];
    const float* wmat  = (const float*)d_in[3];
    const float* bvec  = (const float*)d_in[4];
    const float* gamma = (const float*)d_in[5];
    const float* beta  = (const float*)d_in[6];
    float* out = (float*)d_out;

    char* ws = (char*)d_ws;
    float* stats = (float*)ws;                           // 512 B
    float* w_t   = (float*)(ws + 1024);                  // 147456 B
    float* wo_t  = (float*)(ws + 1024 + 147456);         // 64512 B
    float* off   = (float*)(ws + 215040);                // 27 planes x 4 b = 7077888 B

    hipMemsetAsync(stats, 0, 512, stream);
    prep_kernel<<<144, 256, 0, stream>>>(wmat, w_off, w_t, wo_t);
    off_conv_kernel<<<512, 512, 0, stream>>>(x, wo_t, off);
    deform_kernel<<<512, 512, 0, stream>>>(x, w_t, off, b_off, bvec, out);
    stats_kernel<<<dim3(CHO, NB), 256, 0, stream>>>(out, stats);
    bn_kernel<<<4096, 256, 0, stream>>>(out, stats, gamma, beta);
}

// Round 6
// 234.002 us; speedup vs baseline: 1.2270x; 1.2270x over previous
//
#include <hip/hip_runtime.h>
#include <math.h>

#define CHI 64
#define CHO 64
#define HH 128
#define WW 128
#define NB 4
#define KK 9
#define NOFF 27
#define NOFFP 28              // padded for float2 packing
#define EPSV 1e-5f
#define PLANE (HH * WW)

// packed-fp32 vector types
typedef float v2f __attribute__((ext_vector_type(2)));
// bilinear pair load: only 4-byte alignment guaranteed
typedef float f2v __attribute__((ext_vector_type(2), aligned(4)));

__device__ __forceinline__ v2f pkfma(v2f a, v2f b, v2f c) {
#if __has_builtin(__builtin_elementwise_fma)
    return __builtin_elementwise_fma(a, b, c);
#else
    return a * b + c;
#endif
}

// ---------------- prep: weight transposes ----------------
// w_t[kk][ci][co]   = w[co][ci][kk]          (9*64*64 = 36864 floats)
// wo_t[ci][tap][c28] = w_off[c][ci][tap]     (64*9*28 = 16128 floats, c=27 -> 0)
__global__ __launch_bounds__(256) void prep_kernel(const float* __restrict__ w,
                                                   const float* __restrict__ w_off,
                                                   float* __restrict__ w_t,
                                                   float* __restrict__ wo_t) {
    int i = blockIdx.x * 256 + threadIdx.x;
    if (i < CHO * CHI * KK) {
        int kk = i / (CHI * CHO);
        int r  = i % (CHI * CHO);
        int ci = r / CHO;
        int co = r % CHO;
        w_t[i] = w[(co * CHI + ci) * KK + kk];
    }
    if (i < CHI * KK * NOFFP) {
        int ci  = i / (KK * NOFFP);
        int r   = i % (KK * NOFFP);
        int tap = r / NOFFP;
        int c   = r % NOFFP;
        wo_t[i] = (c < NOFF) ? w_off[(c * CHI + ci) * KK + tap] : 0.f;
    }
}

// ---------------- offset conv ----------------
// 512 threads: w = tid&127, chunk = tid>>7 (4 chunks x 16 ci, SGPR-forced).
// grid 512: blockIdx%8 -> (b, h-half) for XCD L2 locality.
__global__ __launch_bounds__(512) void off_conv_kernel(const float* __restrict__ x,
                                                       const float* __restrict__ wo_t,
                                                       float* __restrict__ off) {
    const int id    = blockIdx.x;
    const int slot  = id & 7;
    const int b     = slot & 3;
    const int h     = (slot >> 2) * 64 + (id >> 3);
    const int w     = threadIdx.x & 127;
    // wave-uniform (flips every 128 = 2 waves) -> force SGPR for scalar weights
    const int chunk = __builtin_amdgcn_readfirstlane(threadIdx.x >> 7);

    v2f acc[NOFFP / 2];
#pragma unroll
    for (int c = 0; c < NOFFP / 2; c++) acc[c] = (v2f)(0.f);

    const float* xb  = x + ((size_t)b * CHI + chunk * 16) * PLANE;
    const float* wob = wo_t + chunk * 16 * KK * NOFFP;

    for (int ci = 0; ci < 16; ci++) {
        const float* plane = xb + ci * PLANE;
        float xv[KK];
#pragma unroll
        for (int ky = 0; ky < 3; ky++) {
            int hr = h - 1 + ky;
            bool rok = (unsigned)hr < HH;
#pragma unroll
            for (int kx = 0; kx < 3; kx++) {
                int wc = w - 1 + kx;
                xv[ky * 3 + kx] = (rok && (unsigned)wc < WW) ? plane[hr * WW + wc] : 0.f;
            }
        }
#pragma unroll
        for (int t = 0; t < KK; t++) {
            v2f xv2 = {xv[t], xv[t]};
            const v2f* wp = (const v2f*)(wob + (ci * KK + t) * NOFFP);
#pragma unroll
            for (int c = 0; c < NOFFP / 2; c++) acc[c] = pkfma(xv2, wp[c], acc[c]);
        }
    }

    __shared__ v2f lacc[3][128][NOFFP / 2];   // 43008 B
    if (chunk > 0) {
#pragma unroll
        for (int c = 0; c < NOFFP / 2; c++) lacc[chunk - 1][w][c] = acc[c];
    }
    __syncthreads();
    if (chunk == 0) {
#pragma unroll
        for (int c = 0; c < NOFFP / 2; c++)
            acc[c] = acc[c] + lacc[0][w][c] + lacc[1][w][c] + lacc[2][w][c];
        float* accs = (float*)acc;
#pragma unroll
        for (int c = 0; c < NOFF; c++)
            off[(((size_t)b * NOFF + c) * HH + h) * WW + w] = accs[c];
    }
}

// ---------------- deform sample + main conv ----------------
// Each block: ONE row (128 px) x ALL 64 co, 2-way ci split (tid>>7, SGPR).
// Gathers per (pixel,kk,ci) sample happen ONCE (R4/R5 did them twice across
// the co-split blocks — VMEM/TA issue throughput was the measured limiter).
// grid 512: blockIdx%8 -> (b, h-half) for XCD L2 locality (~2.2 MB/XCD).
__global__ __launch_bounds__(256, 2) void deform_kernel(const float* __restrict__ x,
                                                        const float* __restrict__ w_t,
                                                        const float* __restrict__ off,
                                                        const float* __restrict__ b_off,
                                                        const float* __restrict__ bias,
                                                        float* __restrict__ out) {
    const int id   = blockIdx.x;
    const int slot = id & 7;
    const int b    = slot >> 1;
    const int h    = (slot & 1) * 64 + (id >> 3);
    const int w    = threadIdx.x & 127;
    // wave-uniform (flips at tid=128, wave boundary) -> SGPR so weight reads
    // stay s_load (R3 lesson: VGPR-based weight base => 3x slowdown)
    const int cih  = __builtin_amdgcn_readfirstlane(threadIdx.x >> 7);

    v2f acc[32];                       // all 64 output channels
#pragma unroll
    for (int j = 0; j < 32; j++) acc[j] = (v2f)(0.f);

    const float* xb   = x + ((size_t)b * CHI + cih * 32) * PLANE;
    const float* offb = off + (size_t)b * NOFF * PLANE + h * WW + w;

#pragma unroll
    for (int kk = 0; kk < KK; kk++) {
        const int ky = kk / 3, kx = kk % 3;
        float dy = offb[(2 * kk) * PLANE]     + b_off[2 * kk];
        float dx = offb[(2 * kk + 1) * PLANE] + b_off[2 * kk + 1];
        float mo = offb[(18 + kk) * PLANE]    + b_off[18 + kk];
        float m  = 1.f / (1.f + __expf(-mo));

        float py = (float)(h - 1 + ky) + dy;
        float px_ = (float)(w - 1 + kx) + dx;
        float fy0 = floorf(py), fx0 = floorf(px_);
        float wy = py - fy0, wx = px_ - fx0;
        int y0 = (int)fy0, x0 = (int)fx0;
        int y1 = y0 + 1, x1 = x0 + 1;
        bool vy0 = (unsigned)y0 < HH, vy1 = (unsigned)y1 < HH;
        bool vx0 = (unsigned)x0 < WW, vx1 = (unsigned)x1 < WW;
        float a00 = (vy0 && vx0) ? (1.f - wy) * (1.f - wx) * m : 0.f;
        float a01 = (vy0 && vx1) ? (1.f - wy) * wx * m : 0.f;
        float a10 = (vy1 && vx0) ? wy * (1.f - wx) * m : 0.f;
        float a11 = (vy1 && vx1) ? wy * wx * m : 0.f;

        // column-pair: one dwordx2 per row, boundary select folded into weights
        int xbc = min(max(x0, 0), WW - 2);
        bool sel = (x0 == xbc);
        v2f cA = { sel ? a00 : a01, sel ? a01 : a00 };
        v2f cB = { sel ? a10 : a11, sel ? a11 : a10 };
        int cy0 = min(max(y0, 0), HH - 1), cy1 = min(max(y1, 0), HH - 1);
        // unsigned -> provably non-negative -> saddr+voffset addressing
        const unsigned o0 = (unsigned)(cy0 * WW + xbc);
        const unsigned o1 = (unsigned)(cy1 * WW + xbc);

        const float* pl = xb;
        const float* wk = w_t + ((size_t)kk * CHI + cih * 32) * CHO;
#pragma unroll 2
        for (int ci = 0; ci < 32; ci++) {
            f2v p0 = *(const f2v*)(pl + o0);
            f2v p1 = *(const f2v*)(pl + o1);
            v2f t = pkfma((v2f)p1, cB, (v2f)p0 * cA);
            float val = t.x + t.y;
            v2f val2 = {val, val};
            const v2f* wp = (const v2f*)(wk + ci * CHO);  // scalar -> s_load
#pragma unroll
            for (int j = 0; j < 32; j++) acc[j] = pkfma(val2, wp[j], acc[j]);
            pl += PLANE;
        }
    }

    __shared__ v2f lacc[128][33];   // 33792 B, padded vs bank conflicts
    if (cih == 1) {
#pragma unroll
        for (int j = 0; j < 32; j++) lacc[w][j] = acc[j];
    }
    __syncthreads();
    if (cih == 0) {
        float* outp = out + ((size_t)b * CHO * HH + h) * WW + w;
#pragma unroll
        for (int j = 0; j < 32; j++) {
            v2f s = acc[j] + lacc[w][j];
            outp[(2 * j) * PLANE]     = s.x + bias[2 * j];
            outp[(2 * j + 1) * PLANE] = s.y + bias[2 * j + 1];
        }
    }
}

// ---------------- per-channel stats (sum, sumsq) ----------------
__global__ __launch_bounds__(256) void stats_kernel(const float* __restrict__ y,
                                                    float* __restrict__ stats) {
    const int co = blockIdx.x;
    const int b  = blockIdx.y;
    const float4* p4 = (const float4*)(y + ((size_t)b * CHO + co) * PLANE);
    float s = 0.f, s2 = 0.f;
    for (int i = threadIdx.x; i < PLANE / 4; i += 256) {
        float4 v = p4[i];
        s  += v.x + v.y + v.z + v.w;
        s2 += v.x * v.x + v.y * v.y + v.z * v.z + v.w * v.w;
    }
#pragma unroll
    for (int o = 32; o > 0; o >>= 1) {
        s  += __shfl_down(s, o, 64);
        s2 += __shfl_down(s2, o, 64);
    }
    __shared__ float ls[4], ls2[4];
    int lane = threadIdx.x & 63, wv = threadIdx.x >> 6;
    if (lane == 0) { ls[wv] = s; ls2[wv] = s2; }
    __syncthreads();
    if (threadIdx.x == 0) {
        float ts = 0.f, t2 = 0.f;
#pragma unroll
        for (int i = 0; i < 4; i++) { ts += ls[i]; t2 += ls2[i]; }
        atomicAdd(&stats[co], ts);
        atomicAdd(&stats[64 + co], t2);
    }
}

// ---------------- BN + ReLU, in place on d_out ----------------
__global__ __launch_bounds__(256) void bn_kernel(float* __restrict__ y,
                                                 const float* __restrict__ stats,
                                                 const float* __restrict__ gamma,
                                                 const float* __restrict__ beta) {
    size_t base = (size_t)blockIdx.x * 1024;           // 16 blocks per (b,co) plane
    int co = (int)((base >> 14) & 63);
    const float inv_n = 1.f / 65536.f;
    float mean = stats[co] * inv_n;
    float var  = stats[64 + co] * inv_n - mean * mean;
    float sc = gamma[co] * rsqrtf(var + EPSV);
    float sh = beta[co] - mean * sc;
    float4* p = (float4*)(y + base);
    float4 v = p[threadIdx.x];
    v.x = fmaxf(fmaf(v.x, sc, sh), 0.f);
    v.y = fmaxf(fmaf(v.y, sc, sh), 0.f);
    v.z = fmaxf(fmaf(v.z, sc, sh), 0.f);
    v.w = fmaxf(fmaf(v.w, sc, sh), 0.f);
    p[threadIdx.x] = v;
}

extern "C" void kernel_launch(void* const* d_in, const int* in_sizes, int n_in,
                              void* d_out, int out_size, void* d_ws, size_t ws_size,
                              hipStream_t stream) {
    const float* x     = (const float*)d_in[0];
    const float* w_off = (const float*)d_in[1];
    const float* b_off = (const float*)d_in[2];
    const float* wmat  = (const float*)d_in[3];
    const float* bvec  = (const float*)d_in[4];
    const float* gamma = (const float*)d_in[5];
    const float* beta  = (const float*)d_in[6];
    float* out = (float*)d_out;

    char* ws = (char*)d_ws;
    float* stats = (float*)ws;                           // 512 B
    float* w_t   = (float*)(ws + 1024);                  // 147456 B
    float* wo_t  = (float*)(ws + 1024 + 147456);         // 64512 B
    float* off   = (float*)(ws + 215040);                // 27 planes x 4 b = 7077888 B

    hipMemsetAsync(stats, 0, 512, stream);
    prep_kernel<<<144, 256, 0, stream>>>(wmat, w_off, w_t, wo_t);
    off_conv_kernel<<<512, 512, 0, stream>>>(x, wo_t, off);
    deform_kernel<<<512, 256, 0, stream>>>(x, w_t, off, b_off, bvec, out);
    stats_kernel<<<dim3(CHO, NB), 256, 0, stream>>>(out, stats);
    bn_kernel<<<4096, 256, 0, stream>>>(out, stats, gamma, beta);
}